// Round 6
// baseline (936.979 us; speedup 1.0000x reference)
//
#include <hip/hip_runtime.h>
#include <stdint.h>

#define TT  4096   // tokens = B*S
#define HD  1024   // hidden
#define NE  8      // experts
#define ID  1024   // expert intermediate
#define SID 2816   // shared intermediate

typedef short s16x8 __attribute__((ext_vector_type(8)));
typedef float f32x4 __attribute__((ext_vector_type(4)));
typedef float f32x4v __attribute__((ext_vector_type(4)));
typedef unsigned short u16x4 __attribute__((ext_vector_type(4)));

__device__ __forceinline__ ushort f2bf(float f) {
  uint32_t u = __float_as_uint(f);
  u += 0x7FFFu + ((u >> 16) & 1u);   // RNE
  return (ushort)(u >> 16);
}

__device__ __forceinline__ void gll16(const ushort* g, ushort* l) {
  __builtin_amdgcn_global_load_lds(
      (const __attribute__((address_space(1))) void*)g,
      (__attribute__((address_space(3))) void*)l, 16, 0, 0);
}

// ---------------- fp32 -> bf16 conversion (all tensors, one launch) --------
struct CvtArgs {
  const float* src[7];
  ushort* dst[7];
  int n[7];
};

__global__ __launch_bounds__(256) void cvt_all(CvtArgs a) {
  int t = blockIdx.y;
  int i = (blockIdx.x * 256 + threadIdx.x) * 4;
  if (i >= a.n[t]) return;
  f32x4v v = *(const f32x4v*)(a.src[t] + i);
  u16x4 o;
  o.x = f2bf(v.x); o.y = f2bf(v.y); o.z = f2bf(v.z); o.w = f2bf(v.w);
  *(u16x4*)(a.dst[t] + i) = o;
}

// ---------------- router: wave per token ----------------------------------
__global__ __launch_bounds__(256) void init_k(int* cnt, int* cur) {
  if (threadIdx.x < NE) { cnt[threadIdx.x] = 0; cur[threadIdx.x] = 0; }
}

__global__ __launch_bounds__(256) void router_k(
    const float* __restrict__ X, const float* __restrict__ gw,
    const float* __restrict__ sgw, int* __restrict__ cnt,
    int* __restrict__ topki, float* __restrict__ topkw,
    float* __restrict__ sgate) {
  int t = blockIdx.x * 4 + (threadIdx.x >> 6);
  int lane = threadIdx.x & 63;
  const float* x = X + (size_t)t * HD;
  float acc[NE];
  #pragma unroll
  for (int e = 0; e < NE; e++) acc[e] = 0.f;
  float sacc = 0.f;
  for (int k = lane; k < HD; k += 64) {
    float xv = x[k];
    #pragma unroll
    for (int e = 0; e < NE; e++) acc[e] += xv * gw[e * HD + k];
    sacc += xv * sgw[k];
  }
  #pragma unroll
  for (int off = 32; off > 0; off >>= 1) {
    #pragma unroll
    for (int e = 0; e < NE; e++) acc[e] += __shfl_down(acc[e], off, 64);
    sacc += __shfl_down(sacc, off, 64);
  }
  if (lane == 0) {
    float m = acc[0];
    #pragma unroll
    for (int e = 1; e < NE; e++) m = fmaxf(m, acc[e]);
    float p[NE];
    #pragma unroll
    for (int e = 0; e < NE; e++) p[e] = __expf(acc[e] - m);
    int i1 = 0;
    #pragma unroll
    for (int e = 1; e < NE; e++) if (p[e] > p[i1]) i1 = e;
    int i2 = (i1 == 0) ? 1 : 0;
    #pragma unroll
    for (int e = 0; e < NE; e++) if (e != i1 && p[e] > p[i2]) i2 = e;
    float inv = 1.f / (p[i1] + p[i2]);   // softmax denom cancels in ratio
    topki[2 * t] = i1; topki[2 * t + 1] = i2;
    topkw[2 * t] = p[i1] * inv; topkw[2 * t + 1] = p[i2] * inv;
    atomicAdd(&cnt[i1], 1);
    atomicAdd(&cnt[i2], 1);
    sgate[t] = 1.f / (1.f + __expf(-sacc));
  }
}

__global__ void scan_k(const int* cnt, int* offs) {
  if (threadIdx.x == 0) {
    int o = 0;
    for (int e = 0; e < NE; e++) { offs[e] = o; o += cnt[e]; }
  }
}

__global__ __launch_bounds__(256) void assign_k(
    const int* __restrict__ topki, const float* __restrict__ topkw,
    const int* __restrict__ offs, int* __restrict__ cur,
    int* __restrict__ tokmap, float* __restrict__ wmap) {
  int t = blockIdx.x * 256 + threadIdx.x;
  #pragma unroll
  for (int kk = 0; kk < 2; kk++) {
    int e = topki[2 * t + kk];
    int pos = offs[e] + atomicAdd(&cur[e], 1);
    tokmap[pos] = t;
    wmap[pos] = topkw[2 * t + kk];
  }
}

// ---------------- GEMM: 256x128x64 tile, 8 waves, phase-split schedule -----
// LDS rows [*][64] bf16 (128B). Swizzle (verified R3/R4, 0 conflicts):
// write side pre-swizzles GLOBAL chunk ((l&7)^((l>>3)&7)), LDS stays linear;
// read side chunk = (ks*4+lhi) ^ (lr&7).
// Phase-split (T3+T4+T5): per K-tile, phases each {issue 1 stage-pair ->
// [ph0: vmcnt(4)+barrier] -> ds_read subtile -> setprio(1) 16 MFMA setprio(0)
// -> barrier}. Stage pairs shifted one phase early => >=2 phases latency
// slack per pair; single counted wait per tile (never 0 in main loop).
constexpr int BM = 256, BN = 128, BK = 64;

template <bool GATHER>
__global__ __launch_bounds__(512, 2) void gemm_gu(
    const ushort* __restrict__ A, const ushort* __restrict__ Wg,
    const ushort* __restrict__ Wu, ushort* __restrict__ Hout,
    const int* __restrict__ tokmap, const int* __restrict__ cnts,
    const int* __restrict__ offs, int M, int N, int K) {
  const int e = blockIdx.z;
  int cnt, seg;
  if (GATHER) { cnt = cnts[e]; seg = offs[e]; } else { cnt = M; seg = 0; }
  const int m0 = blockIdx.x * BM;
  if (m0 >= cnt) return;
  const int n0 = blockIdx.y * BN;
  const ushort* Wge = Wg + (size_t)e * N * K;
  const ushort* Wue = Wu + (size_t)e * N * K;

  __shared__ ushort lA[2][BM * BK];    // 32KB x2
  __shared__ ushort lBg[2][BN * BK];   // 16KB x2
  __shared__ ushort lBu[2][BN * BK];   // 16KB x2  -> 128KB

  const int tid = threadIdx.x;
  const int w = tid >> 6, l = tid & 63;
  const int subrow = w * 8 + (l >> 3);
  const int gchunk = (l & 7) ^ ((l >> 3) & 7);
  const int ldst = w * 512 + l * 8;

  const ushort* ap[4];
  #pragma unroll
  for (int s = 0; s < 4; s++) {
    int row = m0 + s * 64 + subrow;
    if (GATHER) {
      int rr = row < cnt ? row : cnt - 1;
      ap[s] = A + (size_t)tokmap[seg + rr] * K + gchunk * 8;
    } else {
      ap[s] = A + (size_t)row * K + gchunk * 8;
    }
  }
  const ushort *bgp[2], *bup[2];
  #pragma unroll
  for (int s = 0; s < 2; s++) {
    int row = n0 + s * 64 + subrow;
    bgp[s] = Wge + (size_t)row * K + gchunk * 8;
    bup[s] = Wue + (size_t)row * K + gchunk * 8;
  }

  const int nt = K / BK;
  // stage pair p of tile t; buffer parity from UNCLAMPED t (tail-safe),
  // only the global k-offset is clamped (garbage goes to the unread buffer).
  auto ipair = [&](int p, int t) {
    const int b = t & 1;
    const int k0 = (t < nt ? t : nt - 1) * BK;
    if (p == 0) {
      gll16(ap[0] + k0, &lA[b][ldst]);
      gll16(ap[1] + k0, &lA[b][4096 + ldst]);
    } else if (p == 1) {
      gll16(ap[2] + k0, &lA[b][8192 + ldst]);
      gll16(ap[3] + k0, &lA[b][12288 + ldst]);
    } else if (p == 2) {
      gll16(bgp[0] + k0, &lBg[b][ldst]);
      gll16(bgp[1] + k0, &lBg[b][4096 + ldst]);
    } else {
      gll16(bup[0] + k0, &lBu[b][ldst]);
      gll16(bup[1] + k0, &lBu[b][4096 + ldst]);
    }
  };

  f32x4 accG[8][2], accU[8][2];
  #pragma unroll
  for (int i = 0; i < 8; i++)
    #pragma unroll
    for (int j = 0; j < 2; j++) {
      accG[i][j] = f32x4{0.f, 0.f, 0.f, 0.f};
      accU[i][j] = f32x4{0.f, 0.f, 0.f, 0.f};
    }

  const int wm8 = (w >> 2) * 128, wn8 = (w & 3) * 32;
  const int lr = l & 15, lhi = l >> 4;
  const int rsw = lr & 7;

  ipair(0, 0); ipair(1, 0); ipair(2, 0); ipair(3, 0); ipair(0, 1);

  for (int kt = 0; kt < nt; kt++) {
    const int c = kt & 1;
    const ushort* pA  = &lA[c][0];
    const ushort* pBg = &lBg[c][0];
    const ushort* pBu = &lBu[c][0];
    s16x8 af[8], bf[2];

    // ---- phase 0: G, ks=0 ----
    ipair(1, kt + 1);
    asm volatile("s_waitcnt vmcnt(4)" ::: "memory");   // tile kt complete (all waves after barrier)
    __builtin_amdgcn_s_barrier();
    {
      const int kch = (lhi ^ rsw) * 8;
      #pragma unroll
      for (int i = 0; i < 8; i++)
        af[i] = *(const s16x8*)&pA[(wm8 + i * 16 + lr) * 64 + kch];
      #pragma unroll
      for (int j = 0; j < 2; j++)
        bf[j] = *(const s16x8*)&pBg[(wn8 + j * 16 + lr) * 64 + kch];
    }
    __builtin_amdgcn_s_setprio(1);
    #pragma unroll
    for (int i = 0; i < 8; i++)
      #pragma unroll
      for (int j = 0; j < 2; j++)
        accG[i][j] = __builtin_amdgcn_mfma_f32_16x16x32_bf16(af[i], bf[j], accG[i][j], 0, 0, 0);
    __builtin_amdgcn_s_setprio(0);
    __builtin_amdgcn_s_barrier();

    // ---- phase 1: U, ks=0 (reuse af) ----
    ipair(2, kt + 1);
    {
      const int kch = (lhi ^ rsw) * 8;
      #pragma unroll
      for (int j = 0; j < 2; j++)
        bf[j] = *(const s16x8*)&pBu[(wn8 + j * 16 + lr) * 64 + kch];
    }
    __builtin_amdgcn_s_setprio(1);
    #pragma unroll
    for (int i = 0; i < 8; i++)
      #pragma unroll
      for (int j = 0; j < 2; j++)
        accU[i][j] = __builtin_amdgcn_mfma_f32_16x16x32_bf16(af[i], bf[j], accU[i][j], 0, 0, 0);
    __builtin_amdgcn_s_setprio(0);
    __builtin_amdgcn_s_barrier();

    // ---- phase 2: G, ks=1 ----
    ipair(3, kt + 1);
    {
      const int kch = ((4 + lhi) ^ rsw) * 8;
      #pragma unroll
      for (int i = 0; i < 8; i++)
        af[i] = *(const s16x8*)&pA[(wm8 + i * 16 + lr) * 64 + kch];
      #pragma unroll
      for (int j = 0; j < 2; j++)
        bf[j] = *(const s16x8*)&pBg[(wn8 + j * 16 + lr) * 64 + kch];
    }
    __builtin_amdgcn_s_setprio(1);
    #pragma unroll
    for (int i = 0; i < 8; i++)
      #pragma unroll
      for (int j = 0; j < 2; j++)
        accG[i][j] = __builtin_amdgcn_mfma_f32_16x16x32_bf16(af[i], bf[j], accG[i][j], 0, 0, 0);
    __builtin_amdgcn_s_setprio(0);
    __builtin_amdgcn_s_barrier();

    // ---- phase 3: U, ks=1 (reuse af) ----
    ipair(0, kt + 2);
    {
      const int kch = ((4 + lhi) ^ rsw) * 8;
      #pragma unroll
      for (int j = 0; j < 2; j++)
        bf[j] = *(const s16x8*)&pBu[(wn8 + j * 16 + lr) * 64 + kch];
    }
    __builtin_amdgcn_s_setprio(1);
    #pragma unroll
    for (int i = 0; i < 8; i++)
      #pragma unroll
      for (int j = 0; j < 2; j++)
        accU[i][j] = __builtin_amdgcn_mfma_f32_16x16x32_bf16(af[i], bf[j], accU[i][j], 0, 0, 0);
    __builtin_amdgcn_s_setprio(0);
    __builtin_amdgcn_s_barrier();
  }

  #pragma unroll
  for (int i = 0; i < 8; i++) {
    #pragma unroll
    for (int r = 0; r < 4; r++) {
      int m = wm8 + i * 16 + lhi * 4 + r;
      if (m0 + m < cnt) {
        size_t row = (size_t)(seg + m0 + m) * N;
        #pragma unroll
        for (int j = 0; j < 2; j++) {
          int cc = n0 + wn8 + j * 16 + lr;
          float g = accG[i][j][r];
          float u = accU[i][j][r];
          float s = g / (1.f + __expf(-g));   // silu
          Hout[row + cc] = f2bf(s * u);
        }
      }
    }
  }
}

// ---------------- down-proj GEMM (scatter-add or gated store) --------------
template <bool GATHER>
__global__ __launch_bounds__(512, 2) void gemm_down(
    const ushort* __restrict__ A, const ushort* __restrict__ W,
    float* __restrict__ out, const int* __restrict__ tokmap,
    const float* __restrict__ wmap, const int* __restrict__ cnts,
    const int* __restrict__ offs, const float* __restrict__ sgate,
    int M, int N, int K) {
  const int e = blockIdx.z;
  int cnt, seg;
  if (GATHER) { cnt = cnts[e]; seg = offs[e]; } else { cnt = M; seg = 0; }
  const int m0 = blockIdx.x * BM;
  if (m0 >= cnt) return;
  const int n0 = blockIdx.y * BN;
  const ushort* We = W + (size_t)e * N * K;

  __shared__ ushort lA[2][BM * BK];    // 32KB x2
  __shared__ ushort lB[2][BN * BK];    // 16KB x2 -> 96KB

  const int tid = threadIdx.x;
  const int w = tid >> 6, l = tid & 63;
  const int subrow = w * 8 + (l >> 3);
  const int gchunk = (l & 7) ^ ((l >> 3) & 7);
  const int ldst = w * 512 + l * 8;

  const ushort* ap[4];
  #pragma unroll
  for (int s = 0; s < 4; s++) {
    int row = m0 + s * 64 + subrow;
    int rr = row < cnt ? row : cnt - 1;             // A rows slot-indexed
    ap[s] = A + (size_t)(seg + rr) * K + gchunk * 8;
  }
  const ushort* bp[2];
  #pragma unroll
  for (int s = 0; s < 2; s++) {
    int row = n0 + s * 64 + subrow;
    bp[s] = We + (size_t)row * K + gchunk * 8;
  }

  const int nt = K / BK;
  auto ipair = [&](int p, int t) {
    const int b = t & 1;
    const int k0 = (t < nt ? t : nt - 1) * BK;
    if (p == 0) {
      gll16(ap[0] + k0, &lA[b][ldst]);
      gll16(ap[1] + k0, &lA[b][4096 + ldst]);
    } else if (p == 1) {
      gll16(ap[2] + k0, &lA[b][8192 + ldst]);
      gll16(ap[3] + k0, &lA[b][12288 + ldst]);
    } else {
      gll16(bp[0] + k0, &lB[b][ldst]);
      gll16(bp[1] + k0, &lB[b][4096 + ldst]);
    }
  };

  f32x4 acc[8][2];
  #pragma unroll
  for (int i = 0; i < 8; i++)
    #pragma unroll
    for (int j = 0; j < 2; j++) acc[i][j] = f32x4{0.f, 0.f, 0.f, 0.f};

  const int wm8 = (w >> 2) * 128, wn8 = (w & 3) * 32;
  const int lr = l & 15, lhi = l >> 4;
  const int rsw = lr & 7;

  ipair(0, 0); ipair(1, 0); ipair(2, 0);

  for (int kt = 0; kt < nt; kt++) {
    const int c = kt & 1;
    const ushort* pA = &lA[c][0];
    const ushort* pB = &lB[c][0];
    s16x8 af[8], bf[2];

    // ---- phase 0: ks=0 ----
    ipair(0, kt + 1);
    ipair(1, kt + 1);
    asm volatile("s_waitcnt vmcnt(4)" ::: "memory");
    __builtin_amdgcn_s_barrier();
    {
      const int kch = (lhi ^ rsw) * 8;
      #pragma unroll
      for (int i = 0; i < 8; i++)
        af[i] = *(const s16x8*)&pA[(wm8 + i * 16 + lr) * 64 + kch];
      #pragma unroll
      for (int j = 0; j < 2; j++)
        bf[j] = *(const s16x8*)&pB[(wn8 + j * 16 + lr) * 64 + kch];
    }
    __builtin_amdgcn_s_setprio(1);
    #pragma unroll
    for (int i = 0; i < 8; i++)
      #pragma unroll
      for (int j = 0; j < 2; j++)
        acc[i][j] = __builtin_amdgcn_mfma_f32_16x16x32_bf16(af[i], bf[j], acc[i][j], 0, 0, 0);
    __builtin_amdgcn_s_setprio(0);
    __builtin_amdgcn_s_barrier();

    // ---- phase 1: ks=1 ----
    ipair(2, kt + 1);
    {
      const int kch = ((4 + lhi) ^ rsw) * 8;
      #pragma unroll
      for (int i = 0; i < 8; i++)
        af[i] = *(const s16x8*)&pA[(wm8 + i * 16 + lr) * 64 + kch];
      #pragma unroll
      for (int j = 0; j < 2; j++)
        bf[j] = *(const s16x8*)&pB[(wn8 + j * 16 + lr) * 64 + kch];
    }
    __builtin_amdgcn_s_setprio(1);
    #pragma unroll
    for (int i = 0; i < 8; i++)
      #pragma unroll
      for (int j = 0; j < 2; j++)
        acc[i][j] = __builtin_amdgcn_mfma_f32_16x16x32_bf16(af[i], bf[j], acc[i][j], 0, 0, 0);
    __builtin_amdgcn_s_setprio(0);
    __builtin_amdgcn_s_barrier();
  }

  #pragma unroll
  for (int i = 0; i < 8; i++) {
    #pragma unroll
    for (int r = 0; r < 4; r++) {
      int m = wm8 + i * 16 + lhi * 4 + r;
      if (m0 + m < cnt) {
        if (GATHER) {
          int slot = seg + m0 + m;
          int t = tokmap[slot];
          float wv = wmap[slot];
          size_t row = (size_t)t * N;
          #pragma unroll
          for (int j = 0; j < 2; j++) {
            int cc = n0 + wn8 + j * 16 + lr;
            atomicAdd(&out[row + cc], wv * acc[i][j][r]);
          }
        } else {
          int t = m0 + m;
          float wv = sgate[t];
          size_t row = (size_t)t * N;
          #pragma unroll
          for (int j = 0; j < 2; j++) {
            int cc = n0 + wn8 + j * 16 + lr;
            out[row + cc] = wv * acc[i][j][r];
          }
        }
      }
    }
  }
}

// ---------------------------------------------------------------------------
extern "C" void kernel_launch(void* const* d_in, const int* in_sizes, int n_in,
                              void* d_out, int out_size, void* d_ws, size_t ws_size,
                              hipStream_t stream) {
  const float* hs  = (const float*)d_in[0];
  const float* gw  = (const float*)d_in[1];
  const float* wg  = (const float*)d_in[2];
  const float* wu  = (const float*)d_in[3];
  const float* wd  = (const float*)d_in[4];
  const float* swg = (const float*)d_in[5];
  const float* swu = (const float*)d_in[6];
  const float* swd = (const float*)d_in[7];
  const float* sgw = (const float*)d_in[8];
  float* out = (float*)d_out;

  uint8_t* base = (uint8_t*)d_ws;
  size_t off = 0;
  auto give = [&](size_t b) -> void* {
    void* p = base + off;
    off += (b + 255) & ~(size_t)255;
    return p;
  };
  ushort* Xb   = (ushort*)give((size_t)TT * HD * 2);
  ushort* wgB  = (ushort*)give((size_t)NE * ID * HD * 2);
  ushort* wuB  = (ushort*)give((size_t)NE * ID * HD * 2);
  ushort* wdB  = (ushort*)give((size_t)NE * HD * ID * 2);
  ushort* sgB  = (ushort*)give((size_t)SID * HD * 2);
  ushort* suB  = (ushort*)give((size_t)SID * HD * 2);
  ushort* sdB  = (ushort*)give((size_t)HD * SID * 2);
  ushort* Sbuf = (ushort*)give((size_t)TT * SID * 2);
  ushort* Hbuf = (ushort*)give((size_t)2 * TT * ID * 2);
  float* sgate = (float*)give(TT * 4);
  int* topki   = (int*)give(TT * 2 * 4);
  float* topkw = (float*)give(TT * 2 * 4);
  int* tokmap  = (int*)give(2 * TT * 4);
  float* wmap  = (float*)give(2 * TT * 4);
  int* cnt     = (int*)give(256);
  int* offs    = (int*)give(256);
  int* cur     = (int*)give(256);

  // 1. convert everything to bf16
  CvtArgs ca;
  ca.src[0] = hs;  ca.dst[0] = Xb;  ca.n[0] = TT * HD;
  ca.src[1] = wg;  ca.dst[1] = wgB; ca.n[1] = NE * ID * HD;
  ca.src[2] = wu;  ca.dst[2] = wuB; ca.n[2] = NE * ID * HD;
  ca.src[3] = wd;  ca.dst[3] = wdB; ca.n[3] = NE * HD * ID;
  ca.src[4] = swg; ca.dst[4] = sgB; ca.n[4] = SID * HD;
  ca.src[5] = swu; ca.dst[5] = suB; ca.n[5] = SID * HD;
  ca.src[6] = swd; ca.dst[6] = sdB; ca.n[6] = HD * SID;
  cvt_all<<<dim3(8192, 7), 256, 0, stream>>>(ca);

  // 2. routing
  init_k<<<1, 64, 0, stream>>>(cnt, cur);
  router_k<<<TT / 4, 256, 0, stream>>>(hs, gw, sgw, cnt, topki, topkw, sgate);
  scan_k<<<1, 1, 0, stream>>>(cnt, offs);
  assign_k<<<TT / 256, 256, 0, stream>>>(topki, topkw, offs, cur, tokmap, wmap);

  // 3. shared expert (plain store of its term into out)
  gemm_gu<false><<<dim3(TT / BM, SID / BN, 1), 512, 0, stream>>>(
      Xb, sgB, suB, Sbuf, nullptr, nullptr, nullptr, TT, SID, HD);
  gemm_down<false><<<dim3(TT / BM, HD / BN, 1), 512, 0, stream>>>(
      Sbuf, sdB, out, nullptr, nullptr, nullptr, nullptr, sgate, TT, HD, SID);

  // 4. routed experts (atomicAdd on top; stream order guarantees init done)
  gemm_gu<true><<<dim3(2 * TT / BM, ID / BN, NE), 512, 0, stream>>>(
      Xb, wgB, wuB, Hbuf, tokmap, cnt, offs, 0, ID, HD);
  gemm_down<true><<<dim3(2 * TT / BM, HD / BN, NE), 512, 0, stream>>>(
      Hbuf, wdB, out, tokmap, wmap, cnt, offs, nullptr, 0, HD, ID);
}

// Round 7
// 405.055 us; speedup vs baseline: 2.3132x; 2.3132x over previous
//
#include <hip/hip_runtime.h>
#include <stdint.h>

#define TT  4096   // tokens = B*S
#define HD  1024   // hidden
#define NE  8      // experts
#define ID  1024   // expert intermediate
#define SID 2816   // shared intermediate

typedef short s16x8 __attribute__((ext_vector_type(8)));
typedef float f32x4 __attribute__((ext_vector_type(4)));
typedef float f32x4v __attribute__((ext_vector_type(4)));
typedef unsigned short u16x4 __attribute__((ext_vector_type(4)));

__device__ __forceinline__ ushort f2bf(float f) {
  uint32_t u = __float_as_uint(f);
  u += 0x7FFFu + ((u >> 16) & 1u);   // RNE
  return (ushort)(u >> 16);
}

__device__ __forceinline__ float bf2f(ushort u) {
  return __uint_as_float((uint32_t)u << 16);
}

__device__ __forceinline__ void gll16(const ushort* g, ushort* l) {
  __builtin_amdgcn_global_load_lds(
      (const __attribute__((address_space(1))) void*)g,
      (__attribute__((address_space(3))) void*)l, 16, 0, 0);
}

// ---------------- fp32 -> bf16 conversion (all tensors, one launch) --------
struct CvtArgs {
  const float* src[7];
  ushort* dst[7];
  int n[7];
};

__global__ __launch_bounds__(256) void cvt_all(CvtArgs a) {
  int t = blockIdx.y;
  int i = (blockIdx.x * 256 + threadIdx.x) * 4;
  if (i >= a.n[t]) return;
  f32x4v v = *(const f32x4v*)(a.src[t] + i);
  u16x4 o;
  o.x = f2bf(v.x); o.y = f2bf(v.y); o.z = f2bf(v.z); o.w = f2bf(v.w);
  *(u16x4*)(a.dst[t] + i) = o;
}

// ---------------- router ----------------------------------------------------
__global__ __launch_bounds__(256) void init_k(int* cnt, int* cur) {
  if (threadIdx.x < NE) { cnt[threadIdx.x] = 0; cur[threadIdx.x] = 0; }
}

__global__ __launch_bounds__(256) void router_k(
    const float* __restrict__ X, const float* __restrict__ gw,
    const float* __restrict__ sgw, int* __restrict__ cnt,
    int* __restrict__ topki, float* __restrict__ topkw,
    float* __restrict__ sgate) {
  int t = blockIdx.x * 4 + (threadIdx.x >> 6);
  int lane = threadIdx.x & 63;
  const float* x = X + (size_t)t * HD;
  float acc[NE];
  #pragma unroll
  for (int e = 0; e < NE; e++) acc[e] = 0.f;
  float sacc = 0.f;
  for (int k = lane; k < HD; k += 64) {
    float xv = x[k];
    #pragma unroll
    for (int e = 0; e < NE; e++) acc[e] += xv * gw[e * HD + k];
    sacc += xv * sgw[k];
  }
  #pragma unroll
  for (int off = 32; off > 0; off >>= 1) {
    #pragma unroll
    for (int e = 0; e < NE; e++) acc[e] += __shfl_down(acc[e], off, 64);
    sacc += __shfl_down(sacc, off, 64);
  }
  if (lane == 0) {
    float m = acc[0];
    #pragma unroll
    for (int e = 1; e < NE; e++) m = fmaxf(m, acc[e]);
    float p[NE];
    #pragma unroll
    for (int e = 0; e < NE; e++) p[e] = __expf(acc[e] - m);
    int i1 = 0;
    #pragma unroll
    for (int e = 1; e < NE; e++) if (p[e] > p[i1]) i1 = e;
    int i2 = (i1 == 0) ? 1 : 0;
    #pragma unroll
    for (int e = 0; e < NE; e++) if (e != i1 && p[e] > p[i2]) i2 = e;
    float inv = 1.f / (p[i1] + p[i2]);
    topki[2 * t] = i1; topki[2 * t + 1] = i2;
    topkw[2 * t] = p[i1] * inv; topkw[2 * t + 1] = p[i2] * inv;
    atomicAdd(&cnt[i1], 1);
    atomicAdd(&cnt[i2], 1);
    sgate[t] = 1.f / (1.f + __expf(-sacc));
  }
}

__global__ void scan_k(const int* cnt, int* offs) {
  if (threadIdx.x == 0) {
    int o = 0;
    for (int e = 0; e < NE; e++) { offs[e] = o; o += cnt[e]; }
  }
}

__global__ __launch_bounds__(256) void assign_k(
    const int* __restrict__ topki, const float* __restrict__ topkw,
    const int* __restrict__ offs, int* __restrict__ cur,
    int* __restrict__ tokmap, float* __restrict__ wmap,
    int* __restrict__ smap) {
  int t = blockIdx.x * 256 + threadIdx.x;
  #pragma unroll
  for (int kk = 0; kk < 2; kk++) {
    int e = topki[2 * t + kk];
    int pos = offs[e] + atomicAdd(&cur[e], 1);
    tokmap[pos] = t;
    wmap[pos] = topkw[2 * t + kk];
    smap[2 * t + kk] = pos;   // token -> slot inverse map
  }
}

// ---------------- GEMM cores (R3-proven: 128x128x32, 3-buf, swizzled) ------
// LDS rows 64B (32 bf16). Write side pre-swizzles GLOBAL 16B chunk
// ((l&3)^((l>>3)&3)); LDS dest linear (global_load_lds rule); read side
// applies same involution -> 0 bank conflicts (verified R3).
constexpr int BM = 128, BN = 128, BK = 32;

template <bool GATHER>
__device__ __forceinline__ void gu_core(
    const ushort* __restrict__ A, const ushort* __restrict__ Wg,
    const ushort* __restrict__ Wu, ushort* __restrict__ Hout,
    const int* __restrict__ tokmap, int cnt, int seg,
    int mb, int nb, int N, int K) {
  const int m0 = mb * BM;
  if (m0 >= cnt) return;
  const int n0 = nb * BN;

  __shared__ ushort lA[3][BM * BK];
  __shared__ ushort lBg[3][BN * BK];
  __shared__ ushort lBu[3][BN * BK];

  const int tid = threadIdx.x;
  const int wave = tid >> 6, lane = tid & 63;
  const int wm = (wave >> 1) * 64, wn = (wave & 1) * 64;

  const int ar0 = wave * 32 + (lane >> 2);
  const int ar1 = ar0 + 16;
  const int kc = ((lane & 3) ^ ((lane >> 3) & 3)) * 8;

  const ushort *a0p, *a1p;
  if (GATHER) {
    int m_ = m0 + ar0;
    int tk0 = (m_ < cnt) ? tokmap[seg + m_] : 0;
    m_ = m0 + ar1;
    int tk1 = (m_ < cnt) ? tokmap[seg + m_] : 0;
    a0p = A + (size_t)tk0 * K + kc;
    a1p = A + (size_t)tk1 * K + kc;
  } else {
    a0p = A + (size_t)(m0 + ar0) * K + kc;
    a1p = A + (size_t)(m0 + ar1) * K + kc;
  }
  const ushort* bg0 = Wg + (size_t)(n0 + ar0) * K + kc;
  const ushort* bg1 = Wg + (size_t)(n0 + ar1) * K + kc;
  const ushort* bu0 = Wu + (size_t)(n0 + ar0) * K + kc;
  const ushort* bu1 = Wu + (size_t)(n0 + ar1) * K + kc;

  f32x4 accG[4][4], accU[4][4];
  #pragma unroll
  for (int i = 0; i < 4; i++)
    #pragma unroll
    for (int j = 0; j < 4; j++) {
      accG[i][j] = f32x4{0.f, 0.f, 0.f, 0.f};
      accU[i][j] = f32x4{0.f, 0.f, 0.f, 0.f};
    }

  const int lr = lane & 15;
  const int lk = (((lane >> 4) ^ ((lr >> 1) & 3))) * 8;
  const int w32 = wave * 32;

  auto stage = [&](int b, int k0) {
    gll16(a0p + k0, &lA[b][w32 * BK]);
    gll16(a1p + k0, &lA[b][(w32 + 16) * BK]);
    gll16(bg0 + k0, &lBg[b][w32 * BK]);
    gll16(bg1 + k0, &lBg[b][(w32 + 16) * BK]);
    gll16(bu0 + k0, &lBu[b][w32 * BK]);
    gll16(bu1 + k0, &lBu[b][(w32 + 16) * BK]);
  };

  const int nt = K / BK;
  stage(0, 0);
  stage(1, BK);
  int buf = 0;
  for (int t = 0; t < nt; t++) {
    if (t + 2 < nt) {
      int nb2 = buf + 2; if (nb2 >= 3) nb2 -= 3;
      stage(nb2, (t + 2) * BK);
      asm volatile("s_waitcnt vmcnt(12)" ::: "memory");
    } else if (t + 1 < nt) {
      asm volatile("s_waitcnt vmcnt(6)" ::: "memory");
    } else {
      asm volatile("s_waitcnt vmcnt(0)" ::: "memory");
    }
    __builtin_amdgcn_s_barrier();

    s16x8 af[4], bgf[4], buf_[4];
    #pragma unroll
    for (int i = 0; i < 4; i++) {
      af[i]   = *(const s16x8*)&lA [buf][(wm + i * 16 + lr) * BK + lk];
      bgf[i]  = *(const s16x8*)&lBg[buf][(wn + i * 16 + lr) * BK + lk];
      buf_[i] = *(const s16x8*)&lBu[buf][(wn + i * 16 + lr) * BK + lk];
    }
    #pragma unroll
    for (int i = 0; i < 4; i++)
      #pragma unroll
      for (int j = 0; j < 4; j++) {
        accG[i][j] = __builtin_amdgcn_mfma_f32_16x16x32_bf16(af[i], bgf[j], accG[i][j], 0, 0, 0);
        accU[i][j] = __builtin_amdgcn_mfma_f32_16x16x32_bf16(af[i], buf_[j], accU[i][j], 0, 0, 0);
      }
    __builtin_amdgcn_s_barrier();
    buf++; if (buf >= 3) buf = 0;
  }

  const int lrr = (lane >> 4) * 4;
  #pragma unroll
  for (int i = 0; i < 4; i++) {
    #pragma unroll
    for (int r = 0; r < 4; r++) {
      int m = wm + i * 16 + lrr + r;
      if (m0 + m < cnt) {
        size_t row = (size_t)(seg + m0 + m) * N;
        #pragma unroll
        for (int j = 0; j < 4; j++) {
          int c = n0 + wn + j * 16 + lr;
          float g = accG[i][j][r];
          float u = accU[i][j][r];
          float s = g / (1.f + __expf(-g));   // silu
          Hout[row + c] = f2bf(s * u);
        }
      }
    }
  }
}

// down-proj: GATHER -> store raw bf16 rows slot-indexed (combined later);
// shared -> store sgate-scaled fp32 directly to out.
template <bool GATHER>
__device__ __forceinline__ void dn_core(
    const ushort* __restrict__ A, const ushort* __restrict__ W,
    ushort* __restrict__ outB, float* __restrict__ outF,
    const float* __restrict__ sgate, int cnt, int seg,
    int mb, int nb, int N, int K) {
  const int m0 = mb * BM;
  if (m0 >= cnt) return;
  const int n0 = nb * BN;

  __shared__ ushort lA[3][BM * BK];
  __shared__ ushort lB[3][BN * BK];

  const int tid = threadIdx.x;
  const int wave = tid >> 6, lane = tid & 63;
  const int wm = (wave >> 1) * 64, wn = (wave & 1) * 64;

  const int ar0 = wave * 32 + (lane >> 2);
  const int ar1 = ar0 + 16;
  const int kc = ((lane & 3) ^ ((lane >> 3) & 3)) * 8;

  int r0 = m0 + ar0; if (r0 > cnt - 1) r0 = cnt - 1;
  int r1 = m0 + ar1; if (r1 > cnt - 1) r1 = cnt - 1;
  const ushort* a0p = A + (size_t)(seg + r0) * K + kc;
  const ushort* a1p = A + (size_t)(seg + r1) * K + kc;
  const ushort* b0 = W + (size_t)(n0 + ar0) * K + kc;
  const ushort* b1 = W + (size_t)(n0 + ar1) * K + kc;

  f32x4 acc[4][4];
  #pragma unroll
  for (int i = 0; i < 4; i++)
    #pragma unroll
    for (int j = 0; j < 4; j++) acc[i][j] = f32x4{0.f, 0.f, 0.f, 0.f};

  const int lr = lane & 15;
  const int lk = (((lane >> 4) ^ ((lr >> 1) & 3))) * 8;
  const int w32 = wave * 32;

  auto stage = [&](int b, int k0) {
    gll16(a0p + k0, &lA[b][w32 * BK]);
    gll16(a1p + k0, &lA[b][(w32 + 16) * BK]);
    gll16(b0 + k0, &lB[b][w32 * BK]);
    gll16(b1 + k0, &lB[b][(w32 + 16) * BK]);
  };

  const int nt = K / BK;
  stage(0, 0);
  stage(1, BK);
  int buf = 0;
  for (int t = 0; t < nt; t++) {
    if (t + 2 < nt) {
      int nb2 = buf + 2; if (nb2 >= 3) nb2 -= 3;
      stage(nb2, (t + 2) * BK);
      asm volatile("s_waitcnt vmcnt(8)" ::: "memory");
    } else if (t + 1 < nt) {
      asm volatile("s_waitcnt vmcnt(4)" ::: "memory");
    } else {
      asm volatile("s_waitcnt vmcnt(0)" ::: "memory");
    }
    __builtin_amdgcn_s_barrier();

    s16x8 af[4], bf[4];
    #pragma unroll
    for (int i = 0; i < 4; i++) {
      af[i] = *(const s16x8*)&lA[buf][(wm + i * 16 + lr) * BK + lk];
      bf[i] = *(const s16x8*)&lB[buf][(wn + i * 16 + lr) * BK + lk];
    }
    #pragma unroll
    for (int i = 0; i < 4; i++)
      #pragma unroll
      for (int j = 0; j < 4; j++)
        acc[i][j] = __builtin_amdgcn_mfma_f32_16x16x32_bf16(af[i], bf[j], acc[i][j], 0, 0, 0);
    __builtin_amdgcn_s_barrier();
    buf++; if (buf >= 3) buf = 0;
  }

  const int lrr = (lane >> 4) * 4;
  #pragma unroll
  for (int i = 0; i < 4; i++) {
    #pragma unroll
    for (int r = 0; r < 4; r++) {
      int m = wm + i * 16 + lrr + r;
      if (m0 + m < cnt) {
        if (GATHER) {
          size_t row = (size_t)(seg + m0 + m) * N;
          #pragma unroll
          for (int j = 0; j < 4; j++) {
            int c = n0 + wn + j * 16 + lr;
            outB[row + c] = f2bf(acc[i][j][r]);
          }
        } else {
          int t = m0 + m;
          float wv = sgate[t];
          size_t row = (size_t)t * N;
          #pragma unroll
          for (int j = 0; j < 4; j++) {
            int c = n0 + wn + j * 16 + lr;
            outF[row + c] = wv * acc[i][j][r];
          }
        }
      }
    }
  }
}

// ---------------- kernel wrappers (distinct names for rocprof) -------------
// Shared: flat grid + bijective XCD chunk swizzle (nwg % 8 == 0).
__global__ __launch_bounds__(256, 2) void gemm_gu_s(
    const ushort* __restrict__ A, const ushort* __restrict__ Wg,
    const ushort* __restrict__ Wu, ushort* __restrict__ H,
    int M, int N, int K, int nbn) {
  int nwg = gridDim.x, id = blockIdx.x;
  int lg = (id & 7) * (nwg >> 3) + (id >> 3);
  gu_core<false>(A, Wg, Wu, H, nullptr, M, 0, lg / nbn, lg % nbn, N, K);
}

// Routed: expert = fastest grid dim (8) -> expert e lands on XCD e.
__global__ __launch_bounds__(256, 2) void gemm_gu_r(
    const ushort* __restrict__ A, const ushort* __restrict__ Wg,
    const ushort* __restrict__ Wu, ushort* __restrict__ H,
    const int* __restrict__ tokmap, const int* __restrict__ cnts,
    const int* __restrict__ offs, int N, int K) {
  int e = blockIdx.x;
  gu_core<true>(A, Wg + (size_t)e * N * K, Wu + (size_t)e * N * K, H,
                tokmap, cnts[e], offs[e], blockIdx.y, blockIdx.z, N, K);
}

__global__ __launch_bounds__(256, 2) void gemm_dn_s(
    const ushort* __restrict__ A, const ushort* __restrict__ W,
    float* __restrict__ out, const float* __restrict__ sgate,
    int M, int N, int K, int nbn) {
  int nwg = gridDim.x, id = blockIdx.x;
  int lg = (id & 7) * (nwg >> 3) + (id >> 3);
  dn_core<false>(A, W, nullptr, out, sgate, M, 0, lg / nbn, lg % nbn, N, K);
}

__global__ __launch_bounds__(256, 2) void gemm_dn_r(
    const ushort* __restrict__ A, const ushort* __restrict__ W,
    ushort* __restrict__ eo, const int* __restrict__ cnts,
    const int* __restrict__ offs, int N, int K) {
  int e = blockIdx.x;
  dn_core<true>(A, W + (size_t)e * N * K, eo, nullptr, nullptr,
                cnts[e], offs[e], blockIdx.y, blockIdx.z, N, K);
}

// ---------------- final combine: out += w0*eo[s0] + w1*eo[s1] --------------
__global__ __launch_bounds__(256) void combine_k(
    const ushort* __restrict__ eo, const float* __restrict__ topkw,
    const int* __restrict__ smap, float* __restrict__ out) {
  int t = blockIdx.x;
  int c = threadIdx.x * 4;
  int s0 = smap[2 * t], s1 = smap[2 * t + 1];
  float w0 = topkw[2 * t], w1 = topkw[2 * t + 1];
  u16x4 a = *(const u16x4*)&eo[(size_t)s0 * HD + c];
  u16x4 b = *(const u16x4*)&eo[(size_t)s1 * HD + c];
  float* o = out + (size_t)t * HD + c;
  f32x4 ov = *(const f32x4*)o;
  #pragma unroll
  for (int j = 0; j < 4; j++)
    ov[j] += w0 * bf2f(a[j]) + w1 * bf2f(b[j]);
  *(f32x4*)o = ov;
}

// ---------------------------------------------------------------------------
extern "C" void kernel_launch(void* const* d_in, const int* in_sizes, int n_in,
                              void* d_out, int out_size, void* d_ws, size_t ws_size,
                              hipStream_t stream) {
  const float* hs  = (const float*)d_in[0];
  const float* gw  = (const float*)d_in[1];
  const float* wg  = (const float*)d_in[2];
  const float* wu  = (const float*)d_in[3];
  const float* wd  = (const float*)d_in[4];
  const float* swg = (const float*)d_in[5];
  const float* swu = (const float*)d_in[6];
  const float* swd = (const float*)d_in[7];
  const float* sgw = (const float*)d_in[8];
  float* out = (float*)d_out;

  uint8_t* base = (uint8_t*)d_ws;
  size_t off = 0;
  auto give = [&](size_t b) -> void* {
    void* p = base + off;
    off += (b + 255) & ~(size_t)255;
    return p;
  };
  ushort* Xb   = (ushort*)give((size_t)TT * HD * 2);
  ushort* wgB  = (ushort*)give((size_t)NE * ID * HD * 2);
  ushort* wuB  = (ushort*)give((size_t)NE * ID * HD * 2);
  ushort* wdB  = (ushort*)give((size_t)NE * HD * ID * 2);
  ushort* sgB  = (ushort*)give((size_t)SID * HD * 2);
  ushort* suB  = (ushort*)give((size_t)SID * HD * 2);
  ushort* sdB  = (ushort*)give((size_t)HD * SID * 2);
  ushort* Sbuf = (ushort*)give((size_t)TT * SID * 2);  // also reused as eo
  ushort* Hbuf = (ushort*)give((size_t)2 * TT * ID * 2);
  float* sgate = (float*)give(TT * 4);
  int* topki   = (int*)give(TT * 2 * 4);
  float* topkw = (float*)give(TT * 2 * 4);
  int* tokmap  = (int*)give(2 * TT * 4);
  float* wmap  = (float*)give(2 * TT * 4);
  int* smap    = (int*)give(2 * TT * 4);
  int* cnt     = (int*)give(256);
  int* offs    = (int*)give(256);
  int* cur     = (int*)give(256);

  // 1. convert everything to bf16
  CvtArgs ca;
  ca.src[0] = hs;  ca.dst[0] = Xb;  ca.n[0] = TT * HD;
  ca.src[1] = wg;  ca.dst[1] = wgB; ca.n[1] = NE * ID * HD;
  ca.src[2] = wu;  ca.dst[2] = wuB; ca.n[2] = NE * ID * HD;
  ca.src[3] = wd;  ca.dst[3] = wdB; ca.n[3] = NE * HD * ID;
  ca.src[4] = swg; ca.dst[4] = sgB; ca.n[4] = SID * HD;
  ca.src[5] = swu; ca.dst[5] = suB; ca.n[5] = SID * HD;
  ca.src[6] = swd; ca.dst[6] = sdB; ca.n[6] = HD * SID;
  cvt_all<<<dim3(8192, 7), 256, 0, stream>>>(ca);

  // 2. routing
  init_k<<<1, 64, 0, stream>>>(cnt, cur);
  router_k<<<TT / 4, 256, 0, stream>>>(hs, gw, sgw, cnt, topki, topkw, sgate);
  scan_k<<<1, 1, 0, stream>>>(cnt, offs);
  assign_k<<<TT / 256, 256, 0, stream>>>(topki, topkw, offs, cur, tokmap, wmap, smap);

  // 3. shared expert: Sbuf = swiglu(X); out = sgate * (Sbuf @ swd^T)
  gemm_gu_s<<<(TT / BM) * (SID / BN), 256, 0, stream>>>(
      Xb, sgB, suB, Sbuf, TT, SID, HD, SID / BN);
  gemm_dn_s<<<(TT / BM) * (HD / BN), 256, 0, stream>>>(
      Sbuf, sdB, out, sgate, TT, HD, SID, HD / BN);

  // 4. routed experts (expert -> XCD affinity via gridDim.x = 8)
  gemm_gu_r<<<dim3(NE, 2 * TT / BM, ID / BN), 256, 0, stream>>>(
      Xb, wgB, wuB, Hbuf, tokmap, cnt, offs, ID, HD);
  gemm_dn_r<<<dim3(NE, 2 * TT / BM, HD / BN), 256, 0, stream>>>(
      Hbuf, wdB, Sbuf /* = eo, Sbuf is dead now */, cnt, offs, HD, ID);

  // 5. combine routed expert outputs into out (no atomics)
  combine_k<<<TT, 256, 0, stream>>>(Sbuf, topkw, smap, out);
}

// Round 8
// 399.972 us; speedup vs baseline: 2.3426x; 1.0127x over previous
//
#include <hip/hip_runtime.h>
#include <stdint.h>

#define TT  4096   // tokens = B*S
#define HD  1024   // hidden
#define NE  8      // experts
#define ID  1024   // expert intermediate
#define SID 2816   // shared intermediate

typedef short s16x8 __attribute__((ext_vector_type(8)));
typedef float f32x4 __attribute__((ext_vector_type(4)));
typedef float f32x4v __attribute__((ext_vector_type(4)));
typedef unsigned short u16x4 __attribute__((ext_vector_type(4)));

__device__ __forceinline__ ushort f2bf(float f) {
  uint32_t u = __float_as_uint(f);
  u += 0x7FFFu + ((u >> 16) & 1u);   // RNE
  return (ushort)(u >> 16);
}

__device__ __forceinline__ float bf2f(ushort u) {
  return __uint_as_float((uint32_t)u << 16);
}

__device__ __forceinline__ void gll16(const ushort* g, ushort* l) {
  __builtin_amdgcn_global_load_lds(
      (const __attribute__((address_space(1))) void*)g,
      (__attribute__((address_space(3))) void*)l, 16, 0, 0);
}

// ---------------- fp32 -> bf16 conversion (all tensors, one launch) --------
struct CvtArgs {
  const float* src[7];
  ushort* dst[7];
  int n[7];
};

__global__ __launch_bounds__(256) void cvt_all(CvtArgs a) {
  int t = blockIdx.y;
  int i = (blockIdx.x * 256 + threadIdx.x) * 4;
  if (i >= a.n[t]) return;
  f32x4v v = *(const f32x4v*)(a.src[t] + i);
  u16x4 o;
  o.x = f2bf(v.x); o.y = f2bf(v.y); o.z = f2bf(v.z); o.w = f2bf(v.w);
  *(u16x4*)(a.dst[t] + i) = o;
}

// ---------------- router ----------------------------------------------------
__global__ __launch_bounds__(256) void init_k(int* cnt, int* cur) {
  if (threadIdx.x < NE) { cnt[threadIdx.x] = 0; cur[threadIdx.x] = 0; }
}

// R8 rewrite: gw+sgw staged in LDS (36KB); float4 X loads; 16 tokens/block.
// R7's scalar-load version was latency-serialized at 20 VGPRs (111 us).
__global__ __launch_bounds__(256) void router_k(
    const float* __restrict__ X, const float* __restrict__ gw,
    const float* __restrict__ sgw, int* __restrict__ cnt,
    int* __restrict__ topki, float* __restrict__ topkw,
    float* __restrict__ sgate) {
  __shared__ float gwL[(NE + 1) * HD];
  #pragma unroll
  for (int i = 0; i < NE * HD / 1024; i++) {
    int idx = i * 1024 + threadIdx.x * 4;
    *(f32x4*)&gwL[idx] = *(const f32x4*)&gw[idx];
  }
  {
    int idx = threadIdx.x * 4;
    if (idx < HD) *(f32x4*)&gwL[NE * HD + idx] = *(const f32x4*)&sgw[idx];
  }
  __syncthreads();

  const int wave = threadIdx.x >> 6, lane = threadIdx.x & 63;
  #pragma unroll
  for (int tt = 0; tt < 4; tt++) {
    const int t = blockIdx.x * 16 + wave * 4 + tt;
    const float* x = X + (size_t)t * HD;
    float acc[NE + 1];
    #pragma unroll
    for (int e = 0; e <= NE; e++) acc[e] = 0.f;
    #pragma unroll
    for (int p = 0; p < HD / 256; p++) {
      const int k = p * 256 + lane * 4;
      f32x4 xv = *(const f32x4*)&x[k];
      #pragma unroll
      for (int e = 0; e < NE; e++) {
        f32x4 g = *(const f32x4*)&gwL[e * HD + k];
        acc[e] += xv.x * g.x + xv.y * g.y + xv.z * g.z + xv.w * g.w;
      }
      f32x4 s = *(const f32x4*)&gwL[NE * HD + k];
      acc[NE] += xv.x * s.x + xv.y * s.y + xv.z * s.z + xv.w * s.w;
    }
    #pragma unroll
    for (int off = 32; off > 0; off >>= 1)
      #pragma unroll
      for (int e = 0; e <= NE; e++)
        acc[e] += __shfl_xor(acc[e], off, 64);
    if (lane == 0) {
      float m = acc[0];
      #pragma unroll
      for (int e = 1; e < NE; e++) m = fmaxf(m, acc[e]);
      float p[NE];
      #pragma unroll
      for (int e = 0; e < NE; e++) p[e] = __expf(acc[e] - m);
      int i1 = 0;
      #pragma unroll
      for (int e = 1; e < NE; e++) if (p[e] > p[i1]) i1 = e;
      int i2 = (i1 == 0) ? 1 : 0;
      #pragma unroll
      for (int e = 0; e < NE; e++) if (e != i1 && p[e] > p[i2]) i2 = e;
      float inv = 1.f / (p[i1] + p[i2]);
      topki[2 * t] = i1; topki[2 * t + 1] = i2;
      topkw[2 * t] = p[i1] * inv; topkw[2 * t + 1] = p[i2] * inv;
      atomicAdd(&cnt[i1], 1);
      atomicAdd(&cnt[i2], 1);
      sgate[t] = 1.f / (1.f + __expf(-acc[NE]));
    }
  }
}

__global__ void scan_k(const int* cnt, int* offs) {
  if (threadIdx.x == 0) {
    int o = 0;
    for (int e = 0; e < NE; e++) { offs[e] = o; o += cnt[e]; }
  }
}

__global__ __launch_bounds__(256) void assign_k(
    const int* __restrict__ topki, const float* __restrict__ topkw,
    const int* __restrict__ offs, int* __restrict__ cur,
    int* __restrict__ tokmap, float* __restrict__ wmap,
    int* __restrict__ smap) {
  int t = blockIdx.x * 256 + threadIdx.x;
  #pragma unroll
  for (int kk = 0; kk < 2; kk++) {
    int e = topki[2 * t + kk];
    int pos = offs[e] + atomicAdd(&cur[e], 1);
    tokmap[pos] = t;
    wmap[pos] = topkw[2 * t + kk];
    smap[2 * t + kk] = pos;   // token -> slot inverse map
  }
}

// ---------------- GEMM cores (R3-proven: 128x128x32, 3-buf, swizzled) ------
// LDS rows 64B (32 bf16). Write side pre-swizzles GLOBAL 16B chunk
// ((l&3)^((l>>3)&3)); LDS dest linear (global_load_lds rule); read side
// applies same involution -> 0 bank conflicts (verified R3).
constexpr int BM = 128, BN = 128, BK = 32;

template <bool GATHER>
__device__ __forceinline__ void gu_core(
    const ushort* __restrict__ A, const ushort* __restrict__ Wg,
    const ushort* __restrict__ Wu, ushort* __restrict__ Hout,
    const int* __restrict__ tokmap, int cnt, int seg,
    int mb, int nb, int N, int K) {
  const int m0 = mb * BM;
  if (m0 >= cnt) return;
  const int n0 = nb * BN;

  __shared__ ushort lA[3][BM * BK];
  __shared__ ushort lBg[3][BN * BK];
  __shared__ ushort lBu[3][BN * BK];

  const int tid = threadIdx.x;
  const int wave = tid >> 6, lane = tid & 63;
  const int wm = (wave >> 1) * 64, wn = (wave & 1) * 64;

  const int ar0 = wave * 32 + (lane >> 2);
  const int ar1 = ar0 + 16;
  const int kc = ((lane & 3) ^ ((lane >> 3) & 3)) * 8;

  const ushort *a0p, *a1p;
  if (GATHER) {
    int m_ = m0 + ar0;
    int tk0 = (m_ < cnt) ? tokmap[seg + m_] : 0;
    m_ = m0 + ar1;
    int tk1 = (m_ < cnt) ? tokmap[seg + m_] : 0;
    a0p = A + (size_t)tk0 * K + kc;
    a1p = A + (size_t)tk1 * K + kc;
  } else {
    a0p = A + (size_t)(m0 + ar0) * K + kc;
    a1p = A + (size_t)(m0 + ar1) * K + kc;
  }
  const ushort* bg0 = Wg + (size_t)(n0 + ar0) * K + kc;
  const ushort* bg1 = Wg + (size_t)(n0 + ar1) * K + kc;
  const ushort* bu0 = Wu + (size_t)(n0 + ar0) * K + kc;
  const ushort* bu1 = Wu + (size_t)(n0 + ar1) * K + kc;

  f32x4 accG[4][4], accU[4][4];
  #pragma unroll
  for (int i = 0; i < 4; i++)
    #pragma unroll
    for (int j = 0; j < 4; j++) {
      accG[i][j] = f32x4{0.f, 0.f, 0.f, 0.f};
      accU[i][j] = f32x4{0.f, 0.f, 0.f, 0.f};
    }

  const int lr = lane & 15;
  const int lk = (((lane >> 4) ^ ((lr >> 1) & 3))) * 8;
  const int w32 = wave * 32;

  auto stage = [&](int b, int k0) {
    gll16(a0p + k0, &lA[b][w32 * BK]);
    gll16(a1p + k0, &lA[b][(w32 + 16) * BK]);
    gll16(bg0 + k0, &lBg[b][w32 * BK]);
    gll16(bg1 + k0, &lBg[b][(w32 + 16) * BK]);
    gll16(bu0 + k0, &lBu[b][w32 * BK]);
    gll16(bu1 + k0, &lBu[b][(w32 + 16) * BK]);
  };

  const int nt = K / BK;
  stage(0, 0);
  stage(1, BK);
  int buf = 0;
  for (int t = 0; t < nt; t++) {
    if (t + 2 < nt) {
      int nb2 = buf + 2; if (nb2 >= 3) nb2 -= 3;
      stage(nb2, (t + 2) * BK);
      asm volatile("s_waitcnt vmcnt(12)" ::: "memory");
    } else if (t + 1 < nt) {
      asm volatile("s_waitcnt vmcnt(6)" ::: "memory");
    } else {
      asm volatile("s_waitcnt vmcnt(0)" ::: "memory");
    }
    __builtin_amdgcn_s_barrier();

    s16x8 af[4], bgf[4], buf_[4];
    #pragma unroll
    for (int i = 0; i < 4; i++) {
      af[i]   = *(const s16x8*)&lA [buf][(wm + i * 16 + lr) * BK + lk];
      bgf[i]  = *(const s16x8*)&lBg[buf][(wn + i * 16 + lr) * BK + lk];
      buf_[i] = *(const s16x8*)&lBu[buf][(wn + i * 16 + lr) * BK + lk];
    }
    #pragma unroll
    for (int i = 0; i < 4; i++)
      #pragma unroll
      for (int j = 0; j < 4; j++) {
        accG[i][j] = __builtin_amdgcn_mfma_f32_16x16x32_bf16(af[i], bgf[j], accG[i][j], 0, 0, 0);
        accU[i][j] = __builtin_amdgcn_mfma_f32_16x16x32_bf16(af[i], buf_[j], accU[i][j], 0, 0, 0);
      }
    __builtin_amdgcn_s_barrier();
    buf++; if (buf >= 3) buf = 0;
  }

  const int lrr = (lane >> 4) * 4;
  #pragma unroll
  for (int i = 0; i < 4; i++) {
    #pragma unroll
    for (int r = 0; r < 4; r++) {
      int m = wm + i * 16 + lrr + r;
      if (m0 + m < cnt) {
        size_t row = (size_t)(seg + m0 + m) * N;
        #pragma unroll
        for (int j = 0; j < 4; j++) {
          int c = n0 + wn + j * 16 + lr;
          float g = accG[i][j][r];
          float u = accU[i][j][r];
          float s = g / (1.f + __expf(-g));   // silu
          Hout[row + c] = f2bf(s * u);
        }
      }
    }
  }
}

// down-proj: GATHER -> store raw bf16 rows slot-indexed (combined later);
// shared -> store sgate-scaled fp32 directly to out.
template <bool GATHER>
__device__ __forceinline__ void dn_core(
    const ushort* __restrict__ A, const ushort* __restrict__ W,
    ushort* __restrict__ outB, float* __restrict__ outF,
    const float* __restrict__ sgate, int cnt, int seg,
    int mb, int nb, int N, int K) {
  const int m0 = mb * BM;
  if (m0 >= cnt) return;
  const int n0 = nb * BN;

  __shared__ ushort lA[3][BM * BK];
  __shared__ ushort lB[3][BN * BK];

  const int tid = threadIdx.x;
  const int wave = tid >> 6, lane = tid & 63;
  const int wm = (wave >> 1) * 64, wn = (wave & 1) * 64;

  const int ar0 = wave * 32 + (lane >> 2);
  const int ar1 = ar0 + 16;
  const int kc = ((lane & 3) ^ ((lane >> 3) & 3)) * 8;

  int r0 = m0 + ar0; if (r0 > cnt - 1) r0 = cnt - 1;
  int r1 = m0 + ar1; if (r1 > cnt - 1) r1 = cnt - 1;
  const ushort* a0p = A + (size_t)(seg + r0) * K + kc;
  const ushort* a1p = A + (size_t)(seg + r1) * K + kc;
  const ushort* b0 = W + (size_t)(n0 + ar0) * K + kc;
  const ushort* b1 = W + (size_t)(n0 + ar1) * K + kc;

  f32x4 acc[4][4];
  #pragma unroll
  for (int i = 0; i < 4; i++)
    #pragma unroll
    for (int j = 0; j < 4; j++) acc[i][j] = f32x4{0.f, 0.f, 0.f, 0.f};

  const int lr = lane & 15;
  const int lk = (((lane >> 4) ^ ((lr >> 1) & 3))) * 8;
  const int w32 = wave * 32;

  auto stage = [&](int b, int k0) {
    gll16(a0p + k0, &lA[b][w32 * BK]);
    gll16(a1p + k0, &lA[b][(w32 + 16) * BK]);
    gll16(b0 + k0, &lB[b][w32 * BK]);
    gll16(b1 + k0, &lB[b][(w32 + 16) * BK]);
  };

  const int nt = K / BK;
  stage(0, 0);
  stage(1, BK);
  int buf = 0;
  for (int t = 0; t < nt; t++) {
    if (t + 2 < nt) {
      int nb2 = buf + 2; if (nb2 >= 3) nb2 -= 3;
      stage(nb2, (t + 2) * BK);
      asm volatile("s_waitcnt vmcnt(8)" ::: "memory");
    } else if (t + 1 < nt) {
      asm volatile("s_waitcnt vmcnt(4)" ::: "memory");
    } else {
      asm volatile("s_waitcnt vmcnt(0)" ::: "memory");
    }
    __builtin_amdgcn_s_barrier();

    s16x8 af[4], bf[4];
    #pragma unroll
    for (int i = 0; i < 4; i++) {
      af[i] = *(const s16x8*)&lA[buf][(wm + i * 16 + lr) * BK + lk];
      bf[i] = *(const s16x8*)&lB[buf][(wn + i * 16 + lr) * BK + lk];
    }
    #pragma unroll
    for (int i = 0; i < 4; i++)
      #pragma unroll
      for (int j = 0; j < 4; j++)
        acc[i][j] = __builtin_amdgcn_mfma_f32_16x16x32_bf16(af[i], bf[j], acc[i][j], 0, 0, 0);
    __builtin_amdgcn_s_barrier();
    buf++; if (buf >= 3) buf = 0;
  }

  const int lrr = (lane >> 4) * 4;
  #pragma unroll
  for (int i = 0; i < 4; i++) {
    #pragma unroll
    for (int r = 0; r < 4; r++) {
      int m = wm + i * 16 + lrr + r;
      if (m0 + m < cnt) {
        if (GATHER) {
          size_t row = (size_t)(seg + m0 + m) * N;
          #pragma unroll
          for (int j = 0; j < 4; j++) {
            int c = n0 + wn + j * 16 + lr;
            outB[row + c] = f2bf(acc[i][j][r]);
          }
        } else {
          int t = m0 + m;
          float wv = sgate[t];
          size_t row = (size_t)t * N;
          #pragma unroll
          for (int j = 0; j < 4; j++) {
            int c = n0 + wn + j * 16 + lr;
            outF[row + c] = wv * acc[i][j][r];
          }
        }
      }
    }
  }
}

// ---------------- kernel wrappers (distinct names for rocprof) -------------
// Shared: flat grid + bijective XCD chunk swizzle (nwg % 8 == 0).
__global__ __launch_bounds__(256, 2) void gemm_gu_s(
    const ushort* __restrict__ A, const ushort* __restrict__ Wg,
    const ushort* __restrict__ Wu, ushort* __restrict__ H,
    int M, int N, int K, int nbn) {
  int nwg = gridDim.x, id = blockIdx.x;
  int lg = (id & 7) * (nwg >> 3) + (id >> 3);
  gu_core<false>(A, Wg, Wu, H, nullptr, M, 0, lg / nbn, lg % nbn, N, K);
}

// Routed: expert = fastest grid dim (8) -> expert e lands on XCD e.
__global__ __launch_bounds__(256, 2) void gemm_gu_r(
    const ushort* __restrict__ A, const ushort* __restrict__ Wg,
    const ushort* __restrict__ Wu, ushort* __restrict__ H,
    const int* __restrict__ tokmap, const int* __restrict__ cnts,
    const int* __restrict__ offs, int N, int K) {
  int e = blockIdx.x;
  gu_core<true>(A, Wg + (size_t)e * N * K, Wu + (size_t)e * N * K, H,
                tokmap, cnts[e], offs[e], blockIdx.y, blockIdx.z, N, K);
}

__global__ __launch_bounds__(256, 2) void gemm_dn_s(
    const ushort* __restrict__ A, const ushort* __restrict__ W,
    float* __restrict__ out, const float* __restrict__ sgate,
    int M, int N, int K, int nbn) {
  int nwg = gridDim.x, id = blockIdx.x;
  int lg = (id & 7) * (nwg >> 3) + (id >> 3);
  dn_core<false>(A, W, nullptr, out, sgate, M, 0, lg / nbn, lg % nbn, N, K);
}

__global__ __launch_bounds__(256, 2) void gemm_dn_r(
    const ushort* __restrict__ A, const ushort* __restrict__ W,
    ushort* __restrict__ eo, const int* __restrict__ cnts,
    const int* __restrict__ offs, int N, int K) {
  int e = blockIdx.x;
  dn_core<true>(A, W + (size_t)e * N * K, eo, nullptr, nullptr,
                cnts[e], offs[e], blockIdx.y, blockIdx.z, N, K);
}

// ---------------- final combine: out += w0*eo[s0] + w1*eo[s1] --------------
__global__ __launch_bounds__(256) void combine_k(
    const ushort* __restrict__ eo, const float* __restrict__ topkw,
    const int* __restrict__ smap, float* __restrict__ out) {
  int t = blockIdx.x;
  int c = threadIdx.x * 4;
  int s0 = smap[2 * t], s1 = smap[2 * t + 1];
  float w0 = topkw[2 * t], w1 = topkw[2 * t + 1];
  u16x4 a = *(const u16x4*)&eo[(size_t)s0 * HD + c];
  u16x4 b = *(const u16x4*)&eo[(size_t)s1 * HD + c];
  float* o = out + (size_t)t * HD + c;
  f32x4 ov = *(const f32x4*)o;
  #pragma unroll
  for (int j = 0; j < 4; j++)
    ov[j] += w0 * bf2f(a[j]) + w1 * bf2f(b[j]);
  *(f32x4*)o = ov;
}

// ---------------------------------------------------------------------------
extern "C" void kernel_launch(void* const* d_in, const int* in_sizes, int n_in,
                              void* d_out, int out_size, void* d_ws, size_t ws_size,
                              hipStream_t stream) {
  const float* hs  = (const float*)d_in[0];
  const float* gw  = (const float*)d_in[1];
  const float* wg  = (const float*)d_in[2];
  const float* wu  = (const float*)d_in[3];
  const float* wd  = (const float*)d_in[4];
  const float* swg = (const float*)d_in[5];
  const float* swu = (const float*)d_in[6];
  const float* swd = (const float*)d_in[7];
  const float* sgw = (const float*)d_in[8];
  float* out = (float*)d_out;

  uint8_t* base = (uint8_t*)d_ws;
  size_t off = 0;
  auto give = [&](size_t b) -> void* {
    void* p = base + off;
    off += (b + 255) & ~(size_t)255;
    return p;
  };
  ushort* Xb   = (ushort*)give((size_t)TT * HD * 2);
  ushort* wgB  = (ushort*)give((size_t)NE * ID * HD * 2);
  ushort* wuB  = (ushort*)give((size_t)NE * ID * HD * 2);
  ushort* wdB  = (ushort*)give((size_t)NE * HD * ID * 2);
  ushort* sgB  = (ushort*)give((size_t)SID * HD * 2);
  ushort* suB  = (ushort*)give((size_t)SID * HD * 2);
  ushort* sdB  = (ushort*)give((size_t)HD * SID * 2);
  ushort* Sbuf = (ushort*)give((size_t)TT * SID * 2);  // also reused as eo
  ushort* Hbuf = (ushort*)give((size_t)2 * TT * ID * 2);
  float* sgate = (float*)give(TT * 4);
  int* topki   = (int*)give(TT * 2 * 4);
  float* topkw = (float*)give(TT * 2 * 4);
  int* tokmap  = (int*)give(2 * TT * 4);
  float* wmap  = (float*)give(2 * TT * 4);
  int* smap    = (int*)give(2 * TT * 4);
  int* cnt     = (int*)give(256);
  int* offs    = (int*)give(256);
  int* cur     = (int*)give(256);

  // 1. convert everything to bf16
  CvtArgs ca;
  ca.src[0] = hs;  ca.dst[0] = Xb;  ca.n[0] = TT * HD;
  ca.src[1] = wg;  ca.dst[1] = wgB; ca.n[1] = NE * ID * HD;
  ca.src[2] = wu;  ca.dst[2] = wuB; ca.n[2] = NE * ID * HD;
  ca.src[3] = wd;  ca.dst[3] = wdB; ca.n[3] = NE * HD * ID;
  ca.src[4] = swg; ca.dst[4] = sgB; ca.n[4] = SID * HD;
  ca.src[5] = swu; ca.dst[5] = suB; ca.n[5] = SID * HD;
  ca.src[6] = swd; ca.dst[6] = sdB; ca.n[6] = HD * SID;
  cvt_all<<<dim3(8192, 7), 256, 0, stream>>>(ca);

  // 2. routing
  init_k<<<1, 64, 0, stream>>>(cnt, cur);
  router_k<<<TT / 16, 256, 0, stream>>>(hs, gw, sgw, cnt, topki, topkw, sgate);
  scan_k<<<1, 1, 0, stream>>>(cnt, offs);
  assign_k<<<TT / 256, 256, 0, stream>>>(topki, topkw, offs, cur, tokmap, wmap, smap);

  // 3. shared expert: Sbuf = swiglu(X); out = sgate * (Sbuf @ swd^T)
  gemm_gu_s<<<(TT / BM) * (SID / BN), 256, 0, stream>>>(
      Xb, sgB, suB, Sbuf, TT, SID, HD, SID / BN);
  gemm_dn_s<<<(TT / BM) * (HD / BN), 256, 0, stream>>>(
      Sbuf, sdB, out, sgate, TT, HD, SID, HD / BN);

  // 4. routed experts (expert -> XCD affinity via gridDim.x = 8)
  gemm_gu_r<<<dim3(NE, 2 * TT / BM, ID / BN), 256, 0, stream>>>(
      Xb, wgB, wuB, Hbuf, tokmap, cnt, offs, ID, HD);
  gemm_dn_r<<<dim3(NE, 2 * TT / BM, HD / BN), 256, 0, stream>>>(
      Hbuf, wdB, Sbuf /* = eo, Sbuf is dead now */, cnt, offs, HD, ID);

  // 5. combine routed expert outputs into out (no atomics)
  combine_k<<<TT, 256, 0, stream>>>(Sbuf, topkw, smap, out);
}

// Round 9
// 286.702 us; speedup vs baseline: 3.2681x; 1.3951x over previous
//
#include <hip/hip_runtime.h>
#include <stdint.h>

#define TT  4096   // tokens = B*S
#define HD  1024   // hidden
#define NE  8      // experts
#define ID  1024   // expert intermediate
#define SID 2816   // shared intermediate

typedef short s16x8 __attribute__((ext_vector_type(8)));
typedef float f32x4 __attribute__((ext_vector_type(4)));
typedef float f32x4v __attribute__((ext_vector_type(4)));
typedef unsigned short u16x4 __attribute__((ext_vector_type(4)));

__device__ __forceinline__ ushort f2bf(float f) {
  uint32_t u = __float_as_uint(f);
  u += 0x7FFFu + ((u >> 16) & 1u);   // RNE
  return (ushort)(u >> 16);
}

__device__ __forceinline__ float bf2f(ushort u) {
  return __uint_as_float((uint32_t)u << 16);
}

__device__ __forceinline__ void gll16(const ushort* g, ushort* l) {
  __builtin_amdgcn_global_load_lds(
      (const __attribute__((address_space(1))) void*)g,
      (__attribute__((address_space(3))) void*)l, 16, 0, 0);
}

// ---------------- fp32 -> bf16 conversion (all tensors, one launch) --------
struct CvtArgs {
  const float* src[7];
  ushort* dst[7];
  int n[7];
};

__global__ __launch_bounds__(256) void cvt_all(CvtArgs a) {
  int t = blockIdx.y;
  int i = (blockIdx.x * 256 + threadIdx.x) * 4;
  if (i >= a.n[t]) return;
  f32x4v v = *(const f32x4v*)(a.src[t] + i);
  u16x4 o;
  o.x = f2bf(v.x); o.y = f2bf(v.y); o.z = f2bf(v.z); o.w = f2bf(v.w);
  *(u16x4*)(a.dst[t] + i) = o;
}

// ---------------- router (pure: no global atomics) -------------------------
__global__ __launch_bounds__(256) void router_k(
    const float* __restrict__ X, const float* __restrict__ gw,
    const float* __restrict__ sgw,
    int* __restrict__ topki, float* __restrict__ topkw,
    float* __restrict__ sgate) {
  __shared__ float gwL[(NE + 1) * HD];
  #pragma unroll
  for (int i = 0; i < NE * HD / 1024; i++) {
    int idx = i * 1024 + threadIdx.x * 4;
    *(f32x4*)&gwL[idx] = *(const f32x4*)&gw[idx];
  }
  {
    int idx = threadIdx.x * 4;
    if (idx < HD) *(f32x4*)&gwL[NE * HD + idx] = *(const f32x4*)&sgw[idx];
  }
  __syncthreads();

  const int wave = threadIdx.x >> 6, lane = threadIdx.x & 63;
  #pragma unroll
  for (int tt = 0; tt < 4; tt++) {
    const int t = blockIdx.x * 16 + wave * 4 + tt;
    const float* x = X + (size_t)t * HD;
    float acc[NE + 1];
    #pragma unroll
    for (int e = 0; e <= NE; e++) acc[e] = 0.f;
    #pragma unroll
    for (int p = 0; p < HD / 256; p++) {
      const int k = p * 256 + lane * 4;
      f32x4 xv = *(const f32x4*)&x[k];
      #pragma unroll
      for (int e = 0; e < NE; e++) {
        f32x4 g = *(const f32x4*)&gwL[e * HD + k];
        acc[e] += xv.x * g.x + xv.y * g.y + xv.z * g.z + xv.w * g.w;
      }
      f32x4 s = *(const f32x4*)&gwL[NE * HD + k];
      acc[NE] += xv.x * s.x + xv.y * s.y + xv.z * s.z + xv.w * s.w;
    }
    #pragma unroll
    for (int off = 32; off > 0; off >>= 1)
      #pragma unroll
      for (int e = 0; e <= NE; e++)
        acc[e] += __shfl_xor(acc[e], off, 64);
    if (lane == 0) {
      float m = acc[0];
      #pragma unroll
      for (int e = 1; e < NE; e++) m = fmaxf(m, acc[e]);
      float p[NE];
      #pragma unroll
      for (int e = 0; e < NE; e++) p[e] = __expf(acc[e] - m);
      int i1 = 0;
      #pragma unroll
      for (int e = 1; e < NE; e++) if (p[e] > p[i1]) i1 = e;
      int i2 = (i1 == 0) ? 1 : 0;
      #pragma unroll
      for (int e = 0; e < NE; e++) if (e != i1 && p[e] > p[i2]) i2 = e;
      float inv = 1.f / (p[i1] + p[i2]);
      topki[2 * t] = i1; topki[2 * t + 1] = i2;
      topkw[2 * t] = p[i1] * inv; topkw[2 * t + 1] = p[i2] * inv;
      sgate[t] = 1.f / (1.f + __expf(-acc[NE]));
    }
  }
}

// ---------------- binning: single block, LDS atomics only ------------------
// Replaces init/scan/assign and the 8192 same-line GLOBAL atomics (R8's 107us
// router tail). Slot order within an expert segment is arbitrary; every
// output row depends only on its own token row, so out is permutation-
// invariant (bit-identical).
__global__ __launch_bounds__(1024) void binning_k(
    const int* __restrict__ topki, const float* __restrict__ topkw,
    int* __restrict__ cnt, int* __restrict__ offs,
    int* __restrict__ tokmap, float* __restrict__ wmap,
    int* __restrict__ smap) {
  __shared__ int h[NE];
  __shared__ int base[NE];
  const int tid = threadIdx.x;
  if (tid < NE) h[tid] = 0;
  __syncthreads();
  int my_e[8];
  #pragma unroll
  for (int i = 0; i < 8; i++) {
    int s = i * 1024 + tid;
    my_e[i] = topki[s];
    atomicAdd(&h[my_e[i]], 1);
  }
  __syncthreads();
  if (tid == 0) {
    int o = 0;
    for (int e = 0; e < NE; e++) {
      base[e] = o; offs[e] = o; cnt[e] = h[e]; o += h[e];
    }
  }
  __syncthreads();
  #pragma unroll
  for (int i = 0; i < 8; i++) {
    int s = i * 1024 + tid;
    int pos = atomicAdd(&base[my_e[i]], 1);
    tokmap[pos] = s >> 1;
    wmap[pos] = topkw[s];
    smap[s] = pos;
  }
}

// ---------------- GEMM cores (R3-proven: 128x128x32, 3-buf, swizzled) ------
// LDS rows 64B (32 bf16). Write side pre-swizzles GLOBAL 16B chunk
// ((l&3)^((l>>3)&3)); LDS dest linear (global_load_lds rule); read side
// applies same involution -> 0 bank conflicts (verified R3).
constexpr int BM = 128, BN = 128, BK = 32;

template <bool GATHER>
__device__ __forceinline__ void gu_core(
    const ushort* __restrict__ A, const ushort* __restrict__ Wg,
    const ushort* __restrict__ Wu, ushort* __restrict__ Hout,
    const int* __restrict__ tokmap, int cnt, int seg,
    int mb, int nb, int N, int K) {
  const int m0 = mb * BM;
  if (m0 >= cnt) return;
  const int n0 = nb * BN;

  __shared__ ushort lA[3][BM * BK];
  __shared__ ushort lBg[3][BN * BK];
  __shared__ ushort lBu[3][BN * BK];

  const int tid = threadIdx.x;
  const int wave = tid >> 6, lane = tid & 63;
  const int wm = (wave >> 1) * 64, wn = (wave & 1) * 64;

  const int ar0 = wave * 32 + (lane >> 2);
  const int ar1 = ar0 + 16;
  const int kc = ((lane & 3) ^ ((lane >> 3) & 3)) * 8;

  const ushort *a0p, *a1p;
  if (GATHER) {
    int m_ = m0 + ar0;
    int tk0 = (m_ < cnt) ? tokmap[seg + m_] : 0;
    m_ = m0 + ar1;
    int tk1 = (m_ < cnt) ? tokmap[seg + m_] : 0;
    a0p = A + (size_t)tk0 * K + kc;
    a1p = A + (size_t)tk1 * K + kc;
  } else {
    a0p = A + (size_t)(m0 + ar0) * K + kc;
    a1p = A + (size_t)(m0 + ar1) * K + kc;
  }
  const ushort* bg0 = Wg + (size_t)(n0 + ar0) * K + kc;
  const ushort* bg1 = Wg + (size_t)(n0 + ar1) * K + kc;
  const ushort* bu0 = Wu + (size_t)(n0 + ar0) * K + kc;
  const ushort* bu1 = Wu + (size_t)(n0 + ar1) * K + kc;

  f32x4 accG[4][4], accU[4][4];
  #pragma unroll
  for (int i = 0; i < 4; i++)
    #pragma unroll
    for (int j = 0; j < 4; j++) {
      accG[i][j] = f32x4{0.f, 0.f, 0.f, 0.f};
      accU[i][j] = f32x4{0.f, 0.f, 0.f, 0.f};
    }

  const int lr = lane & 15;
  const int lk = (((lane >> 4) ^ ((lr >> 1) & 3))) * 8;
  const int w32 = wave * 32;

  auto stage = [&](int b, int k0) {
    gll16(a0p + k0, &lA[b][w32 * BK]);
    gll16(a1p + k0, &lA[b][(w32 + 16) * BK]);
    gll16(bg0 + k0, &lBg[b][w32 * BK]);
    gll16(bg1 + k0, &lBg[b][(w32 + 16) * BK]);
    gll16(bu0 + k0, &lBu[b][w32 * BK]);
    gll16(bu1 + k0, &lBu[b][(w32 + 16) * BK]);
  };

  const int nt = K / BK;
  stage(0, 0);
  stage(1, BK);
  int buf = 0;
  for (int t = 0; t < nt; t++) {
    if (t + 2 < nt) {
      int nb2 = buf + 2; if (nb2 >= 3) nb2 -= 3;
      stage(nb2, (t + 2) * BK);
      asm volatile("s_waitcnt vmcnt(12)" ::: "memory");
    } else if (t + 1 < nt) {
      asm volatile("s_waitcnt vmcnt(6)" ::: "memory");
    } else {
      asm volatile("s_waitcnt vmcnt(0)" ::: "memory");
    }
    __builtin_amdgcn_s_barrier();

    s16x8 af[4], bgf[4], buf_[4];
    #pragma unroll
    for (int i = 0; i < 4; i++) {
      af[i]   = *(const s16x8*)&lA [buf][(wm + i * 16 + lr) * BK + lk];
      bgf[i]  = *(const s16x8*)&lBg[buf][(wn + i * 16 + lr) * BK + lk];
      buf_[i] = *(const s16x8*)&lBu[buf][(wn + i * 16 + lr) * BK + lk];
    }
    #pragma unroll
    for (int i = 0; i < 4; i++)
      #pragma unroll
      for (int j = 0; j < 4; j++) {
        accG[i][j] = __builtin_amdgcn_mfma_f32_16x16x32_bf16(af[i], bgf[j], accG[i][j], 0, 0, 0);
        accU[i][j] = __builtin_amdgcn_mfma_f32_16x16x32_bf16(af[i], buf_[j], accU[i][j], 0, 0, 0);
      }
    __builtin_amdgcn_s_barrier();
    buf++; if (buf >= 3) buf = 0;
  }

  const int lrr = (lane >> 4) * 4;
  #pragma unroll
  for (int i = 0; i < 4; i++) {
    #pragma unroll
    for (int r = 0; r < 4; r++) {
      int m = wm + i * 16 + lrr + r;
      if (m0 + m < cnt) {
        size_t row = (size_t)(seg + m0 + m) * N;
        #pragma unroll
        for (int j = 0; j < 4; j++) {
          int c = n0 + wn + j * 16 + lr;
          float g = accG[i][j][r];
          float u = accU[i][j][r];
          float s = g / (1.f + __expf(-g));   // silu
          Hout[row + c] = f2bf(s * u);
        }
      }
    }
  }
}

// down-proj: GATHER -> store raw bf16 rows slot-indexed (combined later);
// shared -> store sgate-scaled fp32 directly to out.
template <bool GATHER>
__device__ __forceinline__ void dn_core(
    const ushort* __restrict__ A, const ushort* __restrict__ W,
    ushort* __restrict__ outB, float* __restrict__ outF,
    const float* __restrict__ sgate, int cnt, int seg,
    int mb, int nb, int N, int K) {
  const int m0 = mb * BM;
  if (m0 >= cnt) return;
  const int n0 = nb * BN;

  __shared__ ushort lA[3][BM * BK];
  __shared__ ushort lB[3][BN * BK];

  const int tid = threadIdx.x;
  const int wave = tid >> 6, lane = tid & 63;
  const int wm = (wave >> 1) * 64, wn = (wave & 1) * 64;

  const int ar0 = wave * 32 + (lane >> 2);
  const int ar1 = ar0 + 16;
  const int kc = ((lane & 3) ^ ((lane >> 3) & 3)) * 8;

  int r0 = m0 + ar0; if (r0 > cnt - 1) r0 = cnt - 1;
  int r1 = m0 + ar1; if (r1 > cnt - 1) r1 = cnt - 1;
  const ushort* a0p = A + (size_t)(seg + r0) * K + kc;
  const ushort* a1p = A + (size_t)(seg + r1) * K + kc;
  const ushort* b0 = W + (size_t)(n0 + ar0) * K + kc;
  const ushort* b1 = W + (size_t)(n0 + ar1) * K + kc;

  f32x4 acc[4][4];
  #pragma unroll
  for (int i = 0; i < 4; i++)
    #pragma unroll
    for (int j = 0; j < 4; j++) acc[i][j] = f32x4{0.f, 0.f, 0.f, 0.f};

  const int lr = lane & 15;
  const int lk = (((lane >> 4) ^ ((lr >> 1) & 3))) * 8;
  const int w32 = wave * 32;

  auto stage = [&](int b, int k0) {
    gll16(a0p + k0, &lA[b][w32 * BK]);
    gll16(a1p + k0, &lA[b][(w32 + 16) * BK]);
    gll16(b0 + k0, &lB[b][w32 * BK]);
    gll16(b1 + k0, &lB[b][(w32 + 16) * BK]);
  };

  const int nt = K / BK;
  stage(0, 0);
  stage(1, BK);
  int buf = 0;
  for (int t = 0; t < nt; t++) {
    if (t + 2 < nt) {
      int nb2 = buf + 2; if (nb2 >= 3) nb2 -= 3;
      stage(nb2, (t + 2) * BK);
      asm volatile("s_waitcnt vmcnt(8)" ::: "memory");
    } else if (t + 1 < nt) {
      asm volatile("s_waitcnt vmcnt(4)" ::: "memory");
    } else {
      asm volatile("s_waitcnt vmcnt(0)" ::: "memory");
    }
    __builtin_amdgcn_s_barrier();

    s16x8 af[4], bf[4];
    #pragma unroll
    for (int i = 0; i < 4; i++) {
      af[i] = *(const s16x8*)&lA[buf][(wm + i * 16 + lr) * BK + lk];
      bf[i] = *(const s16x8*)&lB[buf][(wn + i * 16 + lr) * BK + lk];
    }
    #pragma unroll
    for (int i = 0; i < 4; i++)
      #pragma unroll
      for (int j = 0; j < 4; j++)
        acc[i][j] = __builtin_amdgcn_mfma_f32_16x16x32_bf16(af[i], bf[j], acc[i][j], 0, 0, 0);
    __builtin_amdgcn_s_barrier();
    buf++; if (buf >= 3) buf = 0;
  }

  const int lrr = (lane >> 4) * 4;
  #pragma unroll
  for (int i = 0; i < 4; i++) {
    #pragma unroll
    for (int r = 0; r < 4; r++) {
      int m = wm + i * 16 + lrr + r;
      if (m0 + m < cnt) {
        if (GATHER) {
          size_t row = (size_t)(seg + m0 + m) * N;
          #pragma unroll
          for (int j = 0; j < 4; j++) {
            int c = n0 + wn + j * 16 + lr;
            outB[row + c] = f2bf(acc[i][j][r]);
          }
        } else {
          int t = m0 + m;
          float wv = sgate[t];
          size_t row = (size_t)t * N;
          #pragma unroll
          for (int j = 0; j < 4; j++) {
            int c = n0 + wn + j * 16 + lr;
            outF[row + c] = wv * acc[i][j][r];
          }
        }
      }
    }
  }
}

// ---------------- kernel wrappers (distinct names for rocprof) -------------
// Shared: flat grid + bijective XCD chunk swizzle (nwg % 8 == 0).
__global__ __launch_bounds__(256, 2) void gemm_gu_s(
    const ushort* __restrict__ A, const ushort* __restrict__ Wg,
    const ushort* __restrict__ Wu, ushort* __restrict__ H,
    int M, int N, int K, int nbn) {
  int nwg = gridDim.x, id = blockIdx.x;
  int lg = (id & 7) * (nwg >> 3) + (id >> 3);
  gu_core<false>(A, Wg, Wu, H, nullptr, M, 0, lg / nbn, lg % nbn, N, K);
}

// Routed: expert = fastest grid dim (8) -> expert e lands on XCD e.
__global__ __launch_bounds__(256, 2) void gemm_gu_r(
    const ushort* __restrict__ A, const ushort* __restrict__ Wg,
    const ushort* __restrict__ Wu, ushort* __restrict__ H,
    const int* __restrict__ tokmap, const int* __restrict__ cnts,
    const int* __restrict__ offs, int N, int K) {
  int e = blockIdx.x;
  gu_core<true>(A, Wg + (size_t)e * N * K, Wu + (size_t)e * N * K, H,
                tokmap, cnts[e], offs[e], blockIdx.y, blockIdx.z, N, K);
}

__global__ __launch_bounds__(256, 2) void gemm_dn_s(
    const ushort* __restrict__ A, const ushort* __restrict__ W,
    float* __restrict__ out, const float* __restrict__ sgate,
    int M, int N, int K, int nbn) {
  int nwg = gridDim.x, id = blockIdx.x;
  int lg = (id & 7) * (nwg >> 3) + (id >> 3);
  dn_core<false>(A, W, nullptr, out, sgate, M, 0, lg / nbn, lg % nbn, N, K);
}

__global__ __launch_bounds__(256, 2) void gemm_dn_r(
    const ushort* __restrict__ A, const ushort* __restrict__ W,
    ushort* __restrict__ eo, const int* __restrict__ cnts,
    const int* __restrict__ offs, int N, int K) {
  int e = blockIdx.x;
  dn_core<true>(A, W + (size_t)e * N * K, eo, nullptr, nullptr,
                cnts[e], offs[e], blockIdx.y, blockIdx.z, N, K);
}

// ---------------- final combine: out += w0*eo[s0] + w1*eo[s1] --------------
__global__ __launch_bounds__(256) void combine_k(
    const ushort* __restrict__ eo, const float* __restrict__ topkw,
    const int* __restrict__ smap, float* __restrict__ out) {
  int t = blockIdx.x;
  int c = threadIdx.x * 4;
  int s0 = smap[2 * t], s1 = smap[2 * t + 1];
  float w0 = topkw[2 * t], w1 = topkw[2 * t + 1];
  u16x4 a = *(const u16x4*)&eo[(size_t)s0 * HD + c];
  u16x4 b = *(const u16x4*)&eo[(size_t)s1 * HD + c];
  float* o = out + (size_t)t * HD + c;
  f32x4 ov = *(const f32x4*)o;
  #pragma unroll
  for (int j = 0; j < 4; j++)
    ov[j] += w0 * bf2f(a[j]) + w1 * bf2f(b[j]);
  *(f32x4*)o = ov;
}

// ---------------------------------------------------------------------------
extern "C" void kernel_launch(void* const* d_in, const int* in_sizes, int n_in,
                              void* d_out, int out_size, void* d_ws, size_t ws_size,
                              hipStream_t stream) {
  const float* hs  = (const float*)d_in[0];
  const float* gw  = (const float*)d_in[1];
  const float* wg  = (const float*)d_in[2];
  const float* wu  = (const float*)d_in[3];
  const float* wd  = (const float*)d_in[4];
  const float* swg = (const float*)d_in[5];
  const float* swu = (const float*)d_in[6];
  const float* swd = (const float*)d_in[7];
  const float* sgw = (const float*)d_in[8];
  float* out = (float*)d_out;

  uint8_t* base = (uint8_t*)d_ws;
  size_t off = 0;
  auto give = [&](size_t b) -> void* {
    void* p = base + off;
    off += (b + 255) & ~(size_t)255;
    return p;
  };
  ushort* Xb   = (ushort*)give((size_t)TT * HD * 2);
  ushort* wgB  = (ushort*)give((size_t)NE * ID * HD * 2);
  ushort* wuB  = (ushort*)give((size_t)NE * ID * HD * 2);
  ushort* wdB  = (ushort*)give((size_t)NE * HD * ID * 2);
  ushort* sgB  = (ushort*)give((size_t)SID * HD * 2);
  ushort* suB  = (ushort*)give((size_t)SID * HD * 2);
  ushort* sdB  = (ushort*)give((size_t)HD * SID * 2);
  ushort* Sbuf = (ushort*)give((size_t)TT * SID * 2);  // also reused as eo
  ushort* Hbuf = (ushort*)give((size_t)2 * TT * ID * 2);
  float* sgate = (float*)give(TT * 4);
  int* topki   = (int*)give(TT * 2 * 4);
  float* topkw = (float*)give(TT * 2 * 4);
  int* tokmap  = (int*)give(2 * TT * 4);
  float* wmap  = (float*)give(2 * TT * 4);
  int* smap    = (int*)give(2 * TT * 4);
  int* cnt     = (int*)give(256);
  int* offs    = (int*)give(256);

  // 1. convert everything to bf16
  CvtArgs ca;
  ca.src[0] = hs;  ca.dst[0] = Xb;  ca.n[0] = TT * HD;
  ca.src[1] = wg;  ca.dst[1] = wgB; ca.n[1] = NE * ID * HD;
  ca.src[2] = wu;  ca.dst[2] = wuB; ca.n[2] = NE * ID * HD;
  ca.src[3] = wd;  ca.dst[3] = wdB; ca.n[3] = NE * HD * ID;
  ca.src[4] = swg; ca.dst[4] = sgB; ca.n[4] = SID * HD;
  ca.src[5] = swu; ca.dst[5] = suB; ca.n[5] = SID * HD;
  ca.src[6] = swd; ca.dst[6] = sdB; ca.n[6] = HD * SID;
  cvt_all<<<dim3(8192, 7), 256, 0, stream>>>(ca);

  // 2. routing (no global atomics anywhere)
  router_k<<<TT / 16, 256, 0, stream>>>(hs, gw, sgw, topki, topkw, sgate);
  binning_k<<<1, 1024, 0, stream>>>(topki, topkw, cnt, offs, tokmap, wmap, smap);

  // 3. shared expert: Sbuf = swiglu(X); out = sgate * (Sbuf @ swd^T)
  gemm_gu_s<<<(TT / BM) * (SID / BN), 256, 0, stream>>>(
      Xb, sgB, suB, Sbuf, TT, SID, HD, SID / BN);
  gemm_dn_s<<<(TT / BM) * (HD / BN), 256, 0, stream>>>(
      Sbuf, sdB, out, sgate, TT, HD, SID, HD / BN);

  // 4. routed experts (expert -> XCD affinity via gridDim.x = 8)
  gemm_gu_r<<<dim3(NE, 2 * TT / BM, ID / BN), 256, 0, stream>>>(
      Xb, wgB, wuB, Hbuf, tokmap, cnt, offs, ID, HD);
  gemm_dn_r<<<dim3(NE, 2 * TT / BM, HD / BN), 256, 0, stream>>>(
      Hbuf, wdB, Sbuf /* = eo, Sbuf is dead now */, cnt, offs, HD, ID);

  // 5. combine routed expert outputs into out (no atomics)
  combine_k<<<TT, 256, 0, stream>>>(Sbuf, topkw, smap, out);
}